// Round 20
// baseline (173.007 us; speedup 1.0000x reference)
//
#include <hip/hip_runtime.h>

typedef __attribute__((ext_vector_type(8))) __bf16 bf16x8;
typedef __attribute__((ext_vector_type(8))) unsigned short ushort8v;
typedef __attribute__((ext_vector_type(4))) float f32x4;

__device__ __forceinline__ unsigned short f2bf(float f) {
  return __builtin_bit_cast(unsigned short, (__bf16)f);
}

// Swizzled byte offsets (XOR row-bits into the 16B-slot index -> no bank conflicts, G4)
__device__ __forceinline__ int qoff(int row, int colb) {  // 256B rows (A/Q/K[64][128] bf16)
  return row * 256 + (colb ^ ((row & 7) << 4));
}
__device__ __forceinline__ int toff(int row, int colb) {  // 128B rows (VT[128][64], S[64][64] bf16)
  return row * 128 + (colb ^ ((row & 7) << 4));
}

// Barrier that does NOT drain vmcnt: LDS-ordering only (m201-verified pattern).
__device__ __forceinline__ void bar_lds() {
  asm volatile("s_waitcnt lgkmcnt(0)" ::: "memory");
  __builtin_amdgcn_s_barrier();
}

// 32 rows/block, grid 256 (1 block/CU). r19 champion body byte-for-byte, plus T5:
// s_setprio(1)/(0) bracketing each MFMA cluster (G's kk-loop, S's nt-loop, P's pairs).
// Mechanism: within an interval the 8 waves drift — MFMA-issuing waves get priority
// over waves in H's ds_writes / lnred's shfl chain / P's stores, keeping the matrix
// pipe fed (isolated probe; r4's setprio was confounded with redundant-S work).
//   IA(r): xr-pref(r-1) || G(r) GEMM1[cur] (48 MFMA) || H(r+1) pack[nxt] || x-load(r+2)
//   IB(r): S(r) QK^T[cur] || lnred(r+2) || P(r-1) PV+store[nxt]
// 2 lgkm-only barriers/row; all LDS double-buffered by row parity (148.6 KB).
__global__ __launch_bounds__(512, 1) void fused_attn(
    const float* __restrict__ x,
    const float* __restrict__ Wq, const float* __restrict__ Wk, const float* __restrict__ Wv,
    const float* __restrict__ bq, const float* __restrict__ bk, const float* __restrict__ bv,
    const float* __restrict__ ln_w, const float* __restrict__ ln_b,
    float* __restrict__ out) {
  __shared__ __align__(16) unsigned char smem[148608];
  // sA[p]=p*16384; sQ[p]=32768+p*16384; sK[p]=65536+p*16384; sVT[p]=98304+p*16384;
  // sS[p]=131072+p*8192; redS=[2][16]f @147456; pPart=[2][8][16]f @147584
  float* redS  = (float*)(smem + 147456);
  float* pPart = (float*)(smem + 147584);

  const int tid = threadIdx.x;
  const int lane = tid & 63;
  const int w = tid >> 6;            // wave 0..7
  const int l15 = lane & 15;
  const int l4 = lane >> 4;          // 0..3
  const size_t base = (size_t)blockIdx.x * (32 * 8192);

  // ---- persistent: weights (24 VGPR, direct f32 load + inline bf16 convert) ----
  bf16x8 wf[3][4];
  const int col = (w << 4) + l15;
#pragma unroll
  for (int m = 0; m < 3; ++m) {
    const float* Wm = (m == 0) ? Wq : (m == 1 ? Wk : Wv);
    const float* wp = Wm + col * 128 + (l4 << 3);
#pragma unroll
    for (int kk = 0; kk < 4; ++kk) {
      f32x4 a = *(const f32x4*)(wp + kk * 32);
      f32x4 b = *(const f32x4*)(wp + kk * 32 + 4);
      ushort8v t;
#pragma unroll
      for (int j = 0; j < 4; ++j) {
        t[j]     = f2bf(a[j]);
        t[4 + j] = f2bf(b[j]);
      }
      wf[m][kk] = __builtin_bit_cast(bf16x8, t);
    }
  }
  const float biasQ = bq[col], biasK = bk[col], biasV = bv[col];

  const int row_x = tid >> 3;        // 0..63
  const int c0 = (tid & 7) << 4;     // 0..112
  float lw[16], lb[16];
  {
    const float* pw = ln_w + row_x * 128 + c0;
    const float* pb = ln_b + row_x * 128 + c0;
#pragma unroll
    for (int i = 0; i < 4; ++i) {
      float4 a = *(const float4*)(pw + i * 4);
      lw[i*4+0]=a.x; lw[i*4+1]=a.y; lw[i*4+2]=a.z; lw[i*4+3]=a.w;
      float4 b = *(const float4*)(pb + i * 4);
      lb[i*4+0]=b.x; lb[i*4+1]=b.y; lb[i*4+2]=b.z; lb[i*4+3]=b.w;
    }
  }

  // ---- prologue: row0 load+reduce; H(0); row1 load+reduce (paid once per 32 rows) ----
  float xvC[16], xvN[16];
  {
    const float* xp = x + base + (size_t)row_x * 128 + c0;
#pragma unroll
    for (int i = 0; i < 4; ++i) {
      float4 a = *(const float4*)(xp + i * 4);
      xvC[i*4+0]=a.x; xvC[i*4+1]=a.y; xvC[i*4+2]=a.z; xvC[i*4+3]=a.w;
    }
  }
  {
    float s1 = 0.f, s2 = 0.f;
#pragma unroll
    for (int i = 0; i < 16; ++i) { s1 += xvC[i]; s2 += xvC[i] * xvC[i]; }
#pragma unroll
    for (int off = 32; off > 0; off >>= 1) {
      s1 += __shfl_xor(s1, off, 64);
      s2 += __shfl_xor(s2, off, 64);
    }
    if (lane == 0) { redS[w] = s1; redS[8 + w] = s2; }
  }
  bar_lds();  // redS[0] visible
  {
    // H(0): pack row0 -> sA[0]
    float t1 = 0.f, t2 = 0.f;
#pragma unroll
    for (int p = 0; p < 8; ++p) { t1 += redS[p]; t2 += redS[8 + p]; }
    const float mu = t1 * (1.f / 8192.f);
    const float rstd = rsqrtf(t2 * (1.f / 8192.f) - mu * mu + 1e-5f);
    unsigned char* sA0 = smem;
#pragma unroll
    for (int h = 0; h < 2; ++h) {
      ushort8v t;
#pragma unroll
      for (int j = 0; j < 8; ++j)
        t[j] = f2bf((xvC[h*8+j] - mu) * rstd * lw[h*8+j] + lb[h*8+j]);
      *(ushort8v*)(sA0 + qoff(row_x, (c0 << 1) + h * 16)) = t;
    }
    // load row1 + its reduce (exposed once per block)
    const float* xp = x + base + 8192 + (size_t)row_x * 128 + c0;
#pragma unroll
    for (int i = 0; i < 4; ++i) {
      float4 a = *(const float4*)(xp + i * 4);
      xvN[i*4+0]=a.x; xvN[i*4+1]=a.y; xvN[i*4+2]=a.z; xvN[i*4+3]=a.w;
    }
    float s1 = 0.f, s2 = 0.f;
#pragma unroll
    for (int i = 0; i < 16; ++i) { s1 += xvN[i]; s2 += xvN[i] * xvN[i]; }
#pragma unroll
    for (int off = 32; off > 0; off >>= 1) {
      s1 += __shfl_xor(s1, off, 64);
      s2 += __shfl_xor(s2, off, 64);
    }
    if (lane == 0) { redS[16 + w] = s1; redS[24 + w] = s2; }
  }
  bar_lds();  // sA[0] + redS[1] visible
#pragma unroll
  for (int i = 0; i < 16; ++i) xvC[i] = xvN[i];  // xvC = row1

#pragma unroll 1
  for (int r = 0; r < 32; ++r) {
    const int cur = r & 1, nxt = cur ^ 1;
    unsigned char* sAc  = smem + cur * 16384;
    unsigned char* sAn  = smem + nxt * 16384;
    unsigned char* sQc  = smem + 32768 + cur * 16384;
    unsigned char* sKc  = smem + 65536 + cur * 16384;
    unsigned char* sVTc = smem + 98304 + cur * 16384;
    unsigned char* sVTn = smem + 98304 + nxt * 16384;
    unsigned char* sSc  = smem + 131072 + cur * 8192;
    unsigned char* sSn  = smem + 131072 + nxt * 8192;
    float* redC = redS + cur * 16;    // lnred(r+2) target
    float* redN = redS + nxt * 16;    // H(r+1) source
    float* pPc = pPart + cur * 128;
    float* pPn = pPart + nxt * 128;
    const size_t bofs = base + (size_t)r * 8192;

    // ================= IA(r): xr(r-1) prefetch || G(r) || H(r+1) =================
    f32x4 xrP[4];
    if (r >= 1) {
      const size_t bofsP = bofs - 8192;
#pragma unroll
      for (int nt = 0; nt < 4; ++nt) {
        const int l = nt * 16 + l15;
        const int mb = (w << 4) + (l4 << 2);
        xrP[nt] = *(const f32x4*)(x + bofsP + (size_t)l * 128 + mb);
      }
    }
    // G(r): GEMM1 (col-split) from sA[cur]
#pragma unroll
    for (int mt = 0; mt < 4; ++mt) {
      bf16x8 aq[4];
#pragma unroll
      for (int kk = 0; kk < 4; ++kk)
        aq[kk] = *(const bf16x8*)(sAc + qoff(mt * 16 + l15, kk * 64 + (l4 << 4)));
      const int i0m = mt * 16 + (l4 << 2);
      f32x4 aQ = {0,0,0,0}, aK = {0,0,0,0}, aV = {0,0,0,0};
      __builtin_amdgcn_s_setprio(1);   // T5: pure-MFMA cluster
#pragma unroll
      for (int kk = 0; kk < 4; ++kk) {
        aQ = __builtin_amdgcn_mfma_f32_16x16x32_bf16(aq[kk], wf[0][kk], aQ, 0, 0, 0);
        aK = __builtin_amdgcn_mfma_f32_16x16x32_bf16(aq[kk], wf[1][kk], aK, 0, 0, 0);
        aV = __builtin_amdgcn_mfma_f32_16x16x32_bf16(aq[kk], wf[2][kk], aV, 0, 0, 0);
      }
      __builtin_amdgcn_s_setprio(0);
#pragma unroll
      for (int rr = 0; rr < 4; ++rr) {
        float zq = aQ[rr] + biasQ; zq = zq > 0.f ? zq + 1.f : __expf(zq);
        *(unsigned short*)(sQc + qoff(i0m + rr, col * 2)) = f2bf(zq);
        float zk = aK[rr] + biasK; zk = zk > 0.f ? zk + 1.f : __expf(zk);
        *(unsigned short*)(sKc + qoff(i0m + rr, col * 2)) = f2bf(zk);
      }
      ushort4 pk;
      pk.x = f2bf(aV[0] + biasV); pk.y = f2bf(aV[1] + biasV);
      pk.z = f2bf(aV[2] + biasV); pk.w = f2bf(aV[3] + biasV);
      *(ushort4*)(sVTc + toff(col, i0m * 2)) = pk;
    }
    // H(r+1): stats from redS[nxt] (written in IB(r-1)/prologue); pack xvC -> sA[nxt]
    if (r < 31) {
      float t1 = 0.f, t2 = 0.f;
#pragma unroll
      for (int p = 0; p < 8; ++p) { t1 += redN[p]; t2 += redN[8 + p]; }
      const float mu = t1 * (1.f / 8192.f);
      const float rstd = rsqrtf(t2 * (1.f / 8192.f) - mu * mu + 1e-5f);
#pragma unroll
      for (int h = 0; h < 2; ++h) {
        ushort8v t;
#pragma unroll
        for (int j = 0; j < 8; ++j)
          t[j] = f2bf((xvC[h*8+j] - mu) * rstd * lw[h*8+j] + lb[h*8+j]);
        *(ushort8v*)(sAn + qoff(row_x, (c0 << 1) + h * 16)) = t;
      }
      if (r < 30) {  // issue load of row r+2 (reduced in IB(r), packed in IA(r+1))
        const float* xp = x + bofs + 2 * 8192 + (size_t)row_x * 128 + c0;
#pragma unroll
        for (int i = 0; i < 4; ++i) {
          float4 a = *(const float4*)(xp + i * 4);
          xvN[i*4+0]=a.x; xvN[i*4+1]=a.y; xvN[i*4+2]=a.z; xvN[i*4+3]=a.w;
        }
      }
    }
    bar_lds();  // end IA(r)

    // ================= IB(r): S(r) || lnred(r+2) || P(r-1) =================
    // S(r): S = Q K^T from sQ/sK[cur]; rowsum partials -> pPart[cur]; raw S -> sS[cur]
    const int rt = w >> 1;
    const int h2 = w & 1;
    const int i0s = rt * 16 + (l4 << 2);
    {
      bf16x8 aq[4];
#pragma unroll
      for (int kk = 0; kk < 4; ++kk)
        aq[kk] = *(const bf16x8*)(sQc + qoff(rt * 16 + l15, kk * 64 + (l4 << 4)));
      f32x4 accS[2];
      __builtin_amdgcn_s_setprio(1);   // T5: S MFMA cluster (ds_reads interleaved)
#pragma unroll
      for (int nt = 0; nt < 2; ++nt) {
        const int ntg = h2 * 2 + nt;
        f32x4 acc = {0,0,0,0};
#pragma unroll
        for (int kk = 0; kk < 4; ++kk) {
          bf16x8 bk_ = *(const bf16x8*)(sKc + qoff(ntg * 16 + l15, kk * 64 + (l4 << 4)));
          acc = __builtin_amdgcn_mfma_f32_16x16x32_bf16(aq[kk], bk_, acc, 0, 0, 0);
        }
        accS[nt] = acc;
      }
      __builtin_amdgcn_s_setprio(0);
      float p[4];
#pragma unroll
      for (int rr = 0; rr < 4; ++rr) p[rr] = accS[0][rr] + accS[1][rr];
#pragma unroll
      for (int off = 1; off < 16; off <<= 1) {
#pragma unroll
        for (int rr = 0; rr < 4; ++rr) p[rr] += __shfl_xor(p[rr], off, 64);
      }
      if (l15 == 0) {
#pragma unroll
        for (int rr = 0; rr < 4; ++rr)
          pPc[w * 16 + (l4 << 2) + rr] = p[rr];
      }
#pragma unroll
      for (int nt = 0; nt < 2; ++nt) {
        const int ntg = h2 * 2 + nt;
#pragma unroll
        for (int rr = 0; rr < 4; ++rr)
          *(unsigned short*)(sSc + toff(i0s + rr, (ntg * 16 + l15) * 2)) = f2bf(accS[nt][rr]);
      }
    }
    // lnred(r+2): reduce xvN -> redS[cur]
    if (r < 30) {
      float n1 = 0.f, n2 = 0.f;
#pragma unroll
      for (int i = 0; i < 16; ++i) { n1 += xvN[i]; n2 += xvN[i] * xvN[i]; }
#pragma unroll
      for (int off = 32; off > 0; off >>= 1) {
        n1 += __shfl_xor(n1, off, 64);
        n2 += __shfl_xor(n2, off, 64);
      }
      if (lane == 0) { redC[w] = n1; redC[8 + w] = n2; }
    }
    // P(r-1): PV + residual + store from buffers [nxt]
    if (r >= 1) {
      const size_t bofsP = bofs - 8192;
      float nv[4];
#pragma unroll
      for (int nt = 0; nt < 4; ++nt)
        nv[nt] = 1.f / (pPn[nt * 32 + l15] + pPn[nt * 32 + 16 + l15] + 1e-7f);
      bf16x8 av[2];
#pragma unroll
      for (int kk = 0; kk < 2; ++kk)
        av[kk] = *(const bf16x8*)(sVTn + toff((w << 4) + l15, kk * 64 + (l4 << 4)));
#pragma unroll
      for (int nt = 0; nt < 4; ++nt) {
        bf16x8 bs0 = *(const bf16x8*)(sSn + toff(nt * 16 + l15, (l4 << 4)));
        bf16x8 bs1 = *(const bf16x8*)(sSn + toff(nt * 16 + l15, 64 + (l4 << 4)));
        f32x4 acc = {0,0,0,0};
        __builtin_amdgcn_s_setprio(1);   // T5: P MFMA pair
        acc = __builtin_amdgcn_mfma_f32_16x16x32_bf16(av[0], bs0, acc, 0, 0, 0);
        acc = __builtin_amdgcn_mfma_f32_16x16x32_bf16(av[1], bs1, acc, 0, 0, 0);
        __builtin_amdgcn_s_setprio(0);
        const int l = nt * 16 + l15;
        const int mb = (w << 4) + (l4 << 2);
        const size_t idx = bofsP + (size_t)l * 128 + mb;
        f32x4 o;
        o[0] = acc[0] * nv[nt] + xrP[nt][0];
        o[1] = acc[1] * nv[nt] + xrP[nt][1];
        o[2] = acc[2] * nv[nt] + xrP[nt][2];
        o[3] = acc[3] * nv[nt] + xrP[nt][3];
        *(f32x4*)(out + idx) = o;
      }
    }
    bar_lds();  // end IB(r)

    if (r < 30) {
#pragma unroll
      for (int i = 0; i < 16; ++i) xvC[i] = xvN[i];
    }
  }

  // ================= epilogue: P(31) (buffers parity 1) =================
  {
    const size_t bofsP = base + 31 * 8192;
    unsigned char* sVT1 = smem + 98304 + 16384;
    unsigned char* sS1  = smem + 131072 + 8192;
    float* pP1 = pPart + 128;
    f32x4 xr7[4];
#pragma unroll
    for (int nt = 0; nt < 4; ++nt) {
      const int l = nt * 16 + l15;
      const int mb = (w << 4) + (l4 << 2);
      xr7[nt] = *(const f32x4*)(x + bofsP + (size_t)l * 128 + mb);
    }
    float nv[4];
#pragma unroll
    for (int nt = 0; nt < 4; ++nt)
      nv[nt] = 1.f / (pP1[nt * 32 + l15] + pP1[nt * 32 + 16 + l15] + 1e-7f);
    bf16x8 av[2];
#pragma unroll
    for (int kk = 0; kk < 2; ++kk)
      av[kk] = *(const bf16x8*)(sVT1 + toff((w << 4) + l15, kk * 64 + (l4 << 4)));
#pragma unroll
    for (int nt = 0; nt < 4; ++nt) {
      bf16x8 bs0 = *(const bf16x8*)(sS1 + toff(nt * 16 + l15, (l4 << 4)));
      bf16x8 bs1 = *(const bf16x8*)(sS1 + toff(nt * 16 + l15, 64 + (l4 << 4)));
      f32x4 acc = {0,0,0,0};
      acc = __builtin_amdgcn_mfma_f32_16x16x32_bf16(av[0], bs0, acc, 0, 0, 0);
      acc = __builtin_amdgcn_mfma_f32_16x16x32_bf16(av[1], bs1, acc, 0, 0, 0);
      const int l = nt * 16 + l15;
      const int mb = (w << 4) + (l4 << 2);
      const size_t idx = bofsP + (size_t)l * 128 + mb;
      f32x4 o;
      o[0] = acc[0] * nv[nt] + xr7[nt][0];
      o[1] = acc[1] * nv[nt] + xr7[nt][1];
      o[2] = acc[2] * nv[nt] + xr7[nt][2];
      o[3] = acc[3] * nv[nt] + xr7[nt][3];
      *(f32x4*)(out + idx) = o;
    }
  }
}

extern "C" void kernel_launch(void* const* d_in, const int* in_sizes, int n_in,
                              void* d_out, int out_size, void* d_ws, size_t ws_size,
                              hipStream_t stream) {
  const float* x   = (const float*)d_in[0];
  const float* Wq  = (const float*)d_in[1];
  const float* bq  = (const float*)d_in[2];
  const float* Wk  = (const float*)d_in[3];
  const float* bk  = (const float*)d_in[4];
  const float* Wv  = (const float*)d_in[5];
  const float* bv  = (const float*)d_in[6];
  const float* lnw = (const float*)d_in[7];
  const float* lnb = (const float*)d_in[8];
  float* out = (float*)d_out;

  fused_attn<<<256, 512, 0, stream>>>(x, Wq, Wk, Wv, bq, bk, bv, lnw, lnb, out);
}

// Round 21
// 171.633 us; speedup vs baseline: 1.0080x; 1.0080x over previous
//
#include <hip/hip_runtime.h>

typedef __attribute__((ext_vector_type(8))) __bf16 bf16x8;
typedef __attribute__((ext_vector_type(8))) unsigned short ushort8v;
typedef __attribute__((ext_vector_type(4))) float f32x4;

__device__ __forceinline__ unsigned short f2bf(float f) {
  return __builtin_bit_cast(unsigned short, (__bf16)f);
}

// Swizzled byte offsets (XOR row-bits into the 16B-slot index -> no bank conflicts, G4)
__device__ __forceinline__ int qoff(int row, int colb) {  // 256B rows (A/Q/K[64][128] bf16)
  return row * 256 + (colb ^ ((row & 7) << 4));
}
__device__ __forceinline__ int toff(int row, int colb) {  // 128B rows (VT[128][64], S[64][64] bf16)
  return row * 128 + (colb ^ ((row & 7) << 4));
}

// Barrier that does NOT drain vmcnt: LDS-ordering only (m201-verified pattern).
__device__ __forceinline__ void bar_lds() {
  asm volatile("s_waitcnt lgkmcnt(0)" ::: "memory");
  __builtin_amdgcn_s_barrier();
}

// SESSION CHAMPION (r15/r19 structure, 224.5 -> ~171.2 us over the session).
// 32 rows/block, grid 256 (1 block/CU), single launch. Two-row phase-overlapped
// pipeline, 2 lgkm-only barriers/row, all LDS double-buffered by row parity:
//   IA(r): xr-pref(r-1) || G(r) GEMM1[cur] (48 MFMA) || H(r+1) pack[nxt] || x-load(r+2)
//   IB(r): S(r) QK^T[cur] || lnred(r+2) || P(r-1) PV+store[nxt]
// T5 setprio reverted (r20 isolated probe: null-to-negative on this lockstep
// structure). Traffic is compulsory-minimal (533 MB); remaining gap to the ~85us
// HBM floor is per-interval dependency latency at 2 waves/SIMD — all structural
// escapes (wave-split, reg-retention, interval rebalance/flattening) lost to the
// register allocator or scheduler. Next quantified target if continued: 9.4M LDS
// write-bank conflicts in the G/S epilogues (pair-packed b32 writes, est. -2-4%).
__global__ __launch_bounds__(512, 1) void fused_attn(
    const float* __restrict__ x,
    const float* __restrict__ Wq, const float* __restrict__ Wk, const float* __restrict__ Wv,
    const float* __restrict__ bq, const float* __restrict__ bk, const float* __restrict__ bv,
    const float* __restrict__ ln_w, const float* __restrict__ ln_b,
    float* __restrict__ out) {
  __shared__ __align__(16) unsigned char smem[148608];
  // sA[p]=p*16384; sQ[p]=32768+p*16384; sK[p]=65536+p*16384; sVT[p]=98304+p*16384;
  // sS[p]=131072+p*8192; redS=[2][16]f @147456; pPart=[2][8][16]f @147584
  float* redS  = (float*)(smem + 147456);
  float* pPart = (float*)(smem + 147584);

  const int tid = threadIdx.x;
  const int lane = tid & 63;
  const int w = tid >> 6;            // wave 0..7
  const int l15 = lane & 15;
  const int l4 = lane >> 4;          // 0..3
  const size_t base = (size_t)blockIdx.x * (32 * 8192);

  // ---- persistent: weights (24 VGPR, direct f32 load + inline bf16 convert) ----
  bf16x8 wf[3][4];
  const int col = (w << 4) + l15;
#pragma unroll
  for (int m = 0; m < 3; ++m) {
    const float* Wm = (m == 0) ? Wq : (m == 1 ? Wk : Wv);
    const float* wp = Wm + col * 128 + (l4 << 3);
#pragma unroll
    for (int kk = 0; kk < 4; ++kk) {
      f32x4 a = *(const f32x4*)(wp + kk * 32);
      f32x4 b = *(const f32x4*)(wp + kk * 32 + 4);
      ushort8v t;
#pragma unroll
      for (int j = 0; j < 4; ++j) {
        t[j]     = f2bf(a[j]);
        t[4 + j] = f2bf(b[j]);
      }
      wf[m][kk] = __builtin_bit_cast(bf16x8, t);
    }
  }
  const float biasQ = bq[col], biasK = bk[col], biasV = bv[col];

  const int row_x = tid >> 3;        // 0..63
  const int c0 = (tid & 7) << 4;     // 0..112
  float lw[16], lb[16];
  {
    const float* pw = ln_w + row_x * 128 + c0;
    const float* pb = ln_b + row_x * 128 + c0;
#pragma unroll
    for (int i = 0; i < 4; ++i) {
      float4 a = *(const float4*)(pw + i * 4);
      lw[i*4+0]=a.x; lw[i*4+1]=a.y; lw[i*4+2]=a.z; lw[i*4+3]=a.w;
      float4 b = *(const float4*)(pb + i * 4);
      lb[i*4+0]=b.x; lb[i*4+1]=b.y; lb[i*4+2]=b.z; lb[i*4+3]=b.w;
    }
  }

  // ---- prologue: row0 load+reduce; H(0); row1 load+reduce (paid once per 32 rows) ----
  float xvC[16], xvN[16];
  {
    const float* xp = x + base + (size_t)row_x * 128 + c0;
#pragma unroll
    for (int i = 0; i < 4; ++i) {
      float4 a = *(const float4*)(xp + i * 4);
      xvC[i*4+0]=a.x; xvC[i*4+1]=a.y; xvC[i*4+2]=a.z; xvC[i*4+3]=a.w;
    }
  }
  {
    float s1 = 0.f, s2 = 0.f;
#pragma unroll
    for (int i = 0; i < 16; ++i) { s1 += xvC[i]; s2 += xvC[i] * xvC[i]; }
#pragma unroll
    for (int off = 32; off > 0; off >>= 1) {
      s1 += __shfl_xor(s1, off, 64);
      s2 += __shfl_xor(s2, off, 64);
    }
    if (lane == 0) { redS[w] = s1; redS[8 + w] = s2; }
  }
  bar_lds();  // redS[0] visible
  {
    // H(0): pack row0 -> sA[0]
    float t1 = 0.f, t2 = 0.f;
#pragma unroll
    for (int p = 0; p < 8; ++p) { t1 += redS[p]; t2 += redS[8 + p]; }
    const float mu = t1 * (1.f / 8192.f);
    const float rstd = rsqrtf(t2 * (1.f / 8192.f) - mu * mu + 1e-5f);
    unsigned char* sA0 = smem;
#pragma unroll
    for (int h = 0; h < 2; ++h) {
      ushort8v t;
#pragma unroll
      for (int j = 0; j < 8; ++j)
        t[j] = f2bf((xvC[h*8+j] - mu) * rstd * lw[h*8+j] + lb[h*8+j]);
      *(ushort8v*)(sA0 + qoff(row_x, (c0 << 1) + h * 16)) = t;
    }
    // load row1 + its reduce (exposed once per block)
    const float* xp = x + base + 8192 + (size_t)row_x * 128 + c0;
#pragma unroll
    for (int i = 0; i < 4; ++i) {
      float4 a = *(const float4*)(xp + i * 4);
      xvN[i*4+0]=a.x; xvN[i*4+1]=a.y; xvN[i*4+2]=a.z; xvN[i*4+3]=a.w;
    }
    float s1 = 0.f, s2 = 0.f;
#pragma unroll
    for (int i = 0; i < 16; ++i) { s1 += xvN[i]; s2 += xvN[i] * xvN[i]; }
#pragma unroll
    for (int off = 32; off > 0; off >>= 1) {
      s1 += __shfl_xor(s1, off, 64);
      s2 += __shfl_xor(s2, off, 64);
    }
    if (lane == 0) { redS[16 + w] = s1; redS[24 + w] = s2; }
  }
  bar_lds();  // sA[0] + redS[1] visible
#pragma unroll
  for (int i = 0; i < 16; ++i) xvC[i] = xvN[i];  // xvC = row1

#pragma unroll 1
  for (int r = 0; r < 32; ++r) {
    const int cur = r & 1, nxt = cur ^ 1;
    unsigned char* sAc  = smem + cur * 16384;
    unsigned char* sAn  = smem + nxt * 16384;
    unsigned char* sQc  = smem + 32768 + cur * 16384;
    unsigned char* sKc  = smem + 65536 + cur * 16384;
    unsigned char* sVTc = smem + 98304 + cur * 16384;
    unsigned char* sVTn = smem + 98304 + nxt * 16384;
    unsigned char* sSc  = smem + 131072 + cur * 8192;
    unsigned char* sSn  = smem + 131072 + nxt * 8192;
    float* redC = redS + cur * 16;    // lnred(r+2) target
    float* redN = redS + nxt * 16;    // H(r+1) source
    float* pPc = pPart + cur * 128;
    float* pPn = pPart + nxt * 128;
    const size_t bofs = base + (size_t)r * 8192;

    // ================= IA(r): xr(r-1) prefetch || G(r) || H(r+1) =================
    f32x4 xrP[4];
    if (r >= 1) {
      const size_t bofsP = bofs - 8192;
#pragma unroll
      for (int nt = 0; nt < 4; ++nt) {
        const int l = nt * 16 + l15;
        const int mb = (w << 4) + (l4 << 2);
        xrP[nt] = *(const f32x4*)(x + bofsP + (size_t)l * 128 + mb);
      }
    }
    // G(r): GEMM1 (col-split) from sA[cur]
#pragma unroll
    for (int mt = 0; mt < 4; ++mt) {
      bf16x8 aq[4];
#pragma unroll
      for (int kk = 0; kk < 4; ++kk)
        aq[kk] = *(const bf16x8*)(sAc + qoff(mt * 16 + l15, kk * 64 + (l4 << 4)));
      const int i0m = mt * 16 + (l4 << 2);
      f32x4 aQ = {0,0,0,0}, aK = {0,0,0,0}, aV = {0,0,0,0};
#pragma unroll
      for (int kk = 0; kk < 4; ++kk) {
        aQ = __builtin_amdgcn_mfma_f32_16x16x32_bf16(aq[kk], wf[0][kk], aQ, 0, 0, 0);
        aK = __builtin_amdgcn_mfma_f32_16x16x32_bf16(aq[kk], wf[1][kk], aK, 0, 0, 0);
        aV = __builtin_amdgcn_mfma_f32_16x16x32_bf16(aq[kk], wf[2][kk], aV, 0, 0, 0);
      }
#pragma unroll
      for (int rr = 0; rr < 4; ++rr) {
        float zq = aQ[rr] + biasQ; zq = zq > 0.f ? zq + 1.f : __expf(zq);
        *(unsigned short*)(sQc + qoff(i0m + rr, col * 2)) = f2bf(zq);
        float zk = aK[rr] + biasK; zk = zk > 0.f ? zk + 1.f : __expf(zk);
        *(unsigned short*)(sKc + qoff(i0m + rr, col * 2)) = f2bf(zk);
      }
      ushort4 pk;
      pk.x = f2bf(aV[0] + biasV); pk.y = f2bf(aV[1] + biasV);
      pk.z = f2bf(aV[2] + biasV); pk.w = f2bf(aV[3] + biasV);
      *(ushort4*)(sVTc + toff(col, i0m * 2)) = pk;
    }
    // H(r+1): stats from redS[nxt] (written in IB(r-1)/prologue); pack xvC -> sA[nxt]
    if (r < 31) {
      float t1 = 0.f, t2 = 0.f;
#pragma unroll
      for (int p = 0; p < 8; ++p) { t1 += redN[p]; t2 += redN[8 + p]; }
      const float mu = t1 * (1.f / 8192.f);
      const float rstd = rsqrtf(t2 * (1.f / 8192.f) - mu * mu + 1e-5f);
#pragma unroll
      for (int h = 0; h < 2; ++h) {
        ushort8v t;
#pragma unroll
        for (int j = 0; j < 8; ++j)
          t[j] = f2bf((xvC[h*8+j] - mu) * rstd * lw[h*8+j] + lb[h*8+j]);
        *(ushort8v*)(sAn + qoff(row_x, (c0 << 1) + h * 16)) = t;
      }
      if (r < 30) {  // issue load of row r+2 (reduced in IB(r), packed in IA(r+1))
        const float* xp = x + bofs + 2 * 8192 + (size_t)row_x * 128 + c0;
#pragma unroll
        for (int i = 0; i < 4; ++i) {
          float4 a = *(const float4*)(xp + i * 4);
          xvN[i*4+0]=a.x; xvN[i*4+1]=a.y; xvN[i*4+2]=a.z; xvN[i*4+3]=a.w;
        }
      }
    }
    bar_lds();  // end IA(r)

    // ================= IB(r): S(r) || lnred(r+2) || P(r-1) =================
    // S(r): S = Q K^T from sQ/sK[cur]; rowsum partials -> pPart[cur]; raw S -> sS[cur]
    const int rt = w >> 1;
    const int h2 = w & 1;
    const int i0s = rt * 16 + (l4 << 2);
    {
      bf16x8 aq[4];
#pragma unroll
      for (int kk = 0; kk < 4; ++kk)
        aq[kk] = *(const bf16x8*)(sQc + qoff(rt * 16 + l15, kk * 64 + (l4 << 4)));
      f32x4 accS[2];
#pragma unroll
      for (int nt = 0; nt < 2; ++nt) {
        const int ntg = h2 * 2 + nt;
        f32x4 acc = {0,0,0,0};
#pragma unroll
        for (int kk = 0; kk < 4; ++kk) {
          bf16x8 bk_ = *(const bf16x8*)(sKc + qoff(ntg * 16 + l15, kk * 64 + (l4 << 4)));
          acc = __builtin_amdgcn_mfma_f32_16x16x32_bf16(aq[kk], bk_, acc, 0, 0, 0);
        }
        accS[nt] = acc;
      }
      float p[4];
#pragma unroll
      for (int rr = 0; rr < 4; ++rr) p[rr] = accS[0][rr] + accS[1][rr];
#pragma unroll
      for (int off = 1; off < 16; off <<= 1) {
#pragma unroll
        for (int rr = 0; rr < 4; ++rr) p[rr] += __shfl_xor(p[rr], off, 64);
      }
      if (l15 == 0) {
#pragma unroll
        for (int rr = 0; rr < 4; ++rr)
          pPc[w * 16 + (l4 << 2) + rr] = p[rr];
      }
#pragma unroll
      for (int nt = 0; nt < 2; ++nt) {
        const int ntg = h2 * 2 + nt;
#pragma unroll
        for (int rr = 0; rr < 4; ++rr)
          *(unsigned short*)(sSc + toff(i0s + rr, (ntg * 16 + l15) * 2)) = f2bf(accS[nt][rr]);
      }
    }
    // lnred(r+2): reduce xvN -> redS[cur]
    if (r < 30) {
      float n1 = 0.f, n2 = 0.f;
#pragma unroll
      for (int i = 0; i < 16; ++i) { n1 += xvN[i]; n2 += xvN[i] * xvN[i]; }
#pragma unroll
      for (int off = 32; off > 0; off >>= 1) {
        n1 += __shfl_xor(n1, off, 64);
        n2 += __shfl_xor(n2, off, 64);
      }
      if (lane == 0) { redC[w] = n1; redC[8 + w] = n2; }
    }
    // P(r-1): PV + residual + store from buffers [nxt]
    if (r >= 1) {
      const size_t bofsP = bofs - 8192;
      float nv[4];
#pragma unroll
      for (int nt = 0; nt < 4; ++nt)
        nv[nt] = 1.f / (pPn[nt * 32 + l15] + pPn[nt * 32 + 16 + l15] + 1e-7f);
      bf16x8 av[2];
#pragma unroll
      for (int kk = 0; kk < 2; ++kk)
        av[kk] = *(const bf16x8*)(sVTn + toff((w << 4) + l15, kk * 64 + (l4 << 4)));
#pragma unroll
      for (int nt = 0; nt < 4; ++nt) {
        bf16x8 bs0 = *(const bf16x8*)(sSn + toff(nt * 16 + l15, (l4 << 4)));
        bf16x8 bs1 = *(const bf16x8*)(sSn + toff(nt * 16 + l15, 64 + (l4 << 4)));
        f32x4 acc = {0,0,0,0};
        acc = __builtin_amdgcn_mfma_f32_16x16x32_bf16(av[0], bs0, acc, 0, 0, 0);
        acc = __builtin_amdgcn_mfma_f32_16x16x32_bf16(av[1], bs1, acc, 0, 0, 0);
        const int l = nt * 16 + l15;
        const int mb = (w << 4) + (l4 << 2);
        const size_t idx = bofsP + (size_t)l * 128 + mb;
        f32x4 o;
        o[0] = acc[0] * nv[nt] + xrP[nt][0];
        o[1] = acc[1] * nv[nt] + xrP[nt][1];
        o[2] = acc[2] * nv[nt] + xrP[nt][2];
        o[3] = acc[3] * nv[nt] + xrP[nt][3];
        *(f32x4*)(out + idx) = o;
      }
    }
    bar_lds();  // end IB(r)

    if (r < 30) {
#pragma unroll
      for (int i = 0; i < 16; ++i) xvC[i] = xvN[i];
    }
  }

  // ================= epilogue: P(31) (buffers parity 1) =================
  {
    const size_t bofsP = base + 31 * 8192;
    unsigned char* sVT1 = smem + 98304 + 16384;
    unsigned char* sS1  = smem + 131072 + 8192;
    float* pP1 = pPart + 128;
    f32x4 xr7[4];
#pragma unroll
    for (int nt = 0; nt < 4; ++nt) {
      const int l = nt * 16 + l15;
      const int mb = (w << 4) + (l4 << 2);
      xr7[nt] = *(const f32x4*)(x + bofsP + (size_t)l * 128 + mb);
    }
    float nv[4];
#pragma unroll
    for (int nt = 0; nt < 4; ++nt)
      nv[nt] = 1.f / (pP1[nt * 32 + l15] + pP1[nt * 32 + 16 + l15] + 1e-7f);
    bf16x8 av[2];
#pragma unroll
    for (int kk = 0; kk < 2; ++kk)
      av[kk] = *(const bf16x8*)(sVT1 + toff((w << 4) + l15, kk * 64 + (l4 << 4)));
#pragma unroll
    for (int nt = 0; nt < 4; ++nt) {
      bf16x8 bs0 = *(const bf16x8*)(sS1 + toff(nt * 16 + l15, (l4 << 4)));
      bf16x8 bs1 = *(const bf16x8*)(sS1 + toff(nt * 16 + l15, 64 + (l4 << 4)));
      f32x4 acc = {0,0,0,0};
      acc = __builtin_amdgcn_mfma_f32_16x16x32_bf16(av[0], bs0, acc, 0, 0, 0);
      acc = __builtin_amdgcn_mfma_f32_16x16x32_bf16(av[1], bs1, acc, 0, 0, 0);
      const int l = nt * 16 + l15;
      const int mb = (w << 4) + (l4 << 2);
      const size_t idx = bofsP + (size_t)l * 128 + mb;
      f32x4 o;
      o[0] = acc[0] * nv[nt] + xr7[nt][0];
      o[1] = acc[1] * nv[nt] + xr7[nt][1];
      o[2] = acc[2] * nv[nt] + xr7[nt][2];
      o[3] = acc[3] * nv[nt] + xr7[nt][3];
      *(f32x4*)(out + idx) = o;
    }
  }
}

extern "C" void kernel_launch(void* const* d_in, const int* in_sizes, int n_in,
                              void* d_out, int out_size, void* d_ws, size_t ws_size,
                              hipStream_t stream) {
  const float* x   = (const float*)d_in[0];
  const float* Wq  = (const float*)d_in[1];
  const float* bq  = (const float*)d_in[2];
  const float* Wk  = (const float*)d_in[3];
  const float* bk  = (const float*)d_in[4];
  const float* Wv  = (const float*)d_in[5];
  const float* bv  = (const float*)d_in[6];
  const float* lnw = (const float*)d_in[7];
  const float* lnb = (const float*)d_in[8];
  float* out = (float*)d_out;

  fused_attn<<<256, 512, 0, stream>>>(x, Wq, Wk, Wv, bq, bk, bv, lnw, lnb, out);
}

// Round 22
// 171.288 us; speedup vs baseline: 1.0100x; 1.0020x over previous
//
#include <hip/hip_runtime.h>

typedef __attribute__((ext_vector_type(8))) __bf16 bf16x8;
typedef __attribute__((ext_vector_type(8))) unsigned short ushort8v;
typedef __attribute__((ext_vector_type(4))) float f32x4;

__device__ __forceinline__ unsigned short f2bf(float f) {
  return __builtin_bit_cast(unsigned short, (__bf16)f);
}

// Swizzled byte offsets. Two XOR bits:
//  (row&7)<<4  — original 16B-slot swizzle (G4).
//  (row&8)<<2  — NEW: 32B (8-bank) shift separating rows that differ by 8. The b16
//  epilogue stores hit rows {rr, rr+4, rr+8, rr+12} across the four l4 groups; groups
//  (0,2) and (1,3) had identical swizzle and bank-wrapped addresses -> 4 lanes/bank.
//  The extra bit puts the four groups on four disjoint 8-bank sets -> 2/bank (free).
//  All accesses route through these functions, so the layout stays self-consistent.
__device__ __forceinline__ int qoff(int row, int colb) {  // 256B rows (A/Q/K[64][128] bf16)
  return row * 256 + (colb ^ ((row & 7) << 4) ^ ((row & 8) << 2));
}
__device__ __forceinline__ int toff(int row, int colb) {  // 128B rows (VT[128][64], S[64][64] bf16)
  return row * 128 + (colb ^ ((row & 7) << 4) ^ ((row & 8) << 2));
}

// Barrier that does NOT drain vmcnt: LDS-ordering only (m201-verified pattern).
__device__ __forceinline__ void bar_lds() {
  asm volatile("s_waitcnt lgkmcnt(0)" ::: "memory");
  __builtin_amdgcn_s_barrier();
}

// 32 rows/block, grid 256 (1 block/CU), single launch. r21 champion body, only the
// swizzle functions changed (second XOR bit; see qoff/toff comment).
//   IA(r): xr-pref(r-1) || G(r) GEMM1[cur] (48 MFMA) || H(r+1) pack[nxt] || x-load(r+2)
//   IB(r): S(r) QK^T[cur] || lnred(r+2) || P(r-1) PV+store[nxt]
// 2 lgkm-only barriers/row; all LDS double-buffered by row parity (148.6 KB).
__global__ __launch_bounds__(512, 1) void fused_attn(
    const float* __restrict__ x,
    const float* __restrict__ Wq, const float* __restrict__ Wk, const float* __restrict__ Wv,
    const float* __restrict__ bq, const float* __restrict__ bk, const float* __restrict__ bv,
    const float* __restrict__ ln_w, const float* __restrict__ ln_b,
    float* __restrict__ out) {
  __shared__ __align__(16) unsigned char smem[148608];
  // sA[p]=p*16384; sQ[p]=32768+p*16384; sK[p]=65536+p*16384; sVT[p]=98304+p*16384;
  // sS[p]=131072+p*8192; redS=[2][16]f @147456; pPart=[2][8][16]f @147584
  float* redS  = (float*)(smem + 147456);
  float* pPart = (float*)(smem + 147584);

  const int tid = threadIdx.x;
  const int lane = tid & 63;
  const int w = tid >> 6;            // wave 0..7
  const int l15 = lane & 15;
  const int l4 = lane >> 4;          // 0..3
  const size_t base = (size_t)blockIdx.x * (32 * 8192);

  // ---- persistent: weights (24 VGPR, direct f32 load + inline bf16 convert) ----
  bf16x8 wf[3][4];
  const int col = (w << 4) + l15;
#pragma unroll
  for (int m = 0; m < 3; ++m) {
    const float* Wm = (m == 0) ? Wq : (m == 1 ? Wk : Wv);
    const float* wp = Wm + col * 128 + (l4 << 3);
#pragma unroll
    for (int kk = 0; kk < 4; ++kk) {
      f32x4 a = *(const f32x4*)(wp + kk * 32);
      f32x4 b = *(const f32x4*)(wp + kk * 32 + 4);
      ushort8v t;
#pragma unroll
      for (int j = 0; j < 4; ++j) {
        t[j]     = f2bf(a[j]);
        t[4 + j] = f2bf(b[j]);
      }
      wf[m][kk] = __builtin_bit_cast(bf16x8, t);
    }
  }
  const float biasQ = bq[col], biasK = bk[col], biasV = bv[col];

  const int row_x = tid >> 3;        // 0..63
  const int c0 = (tid & 7) << 4;     // 0..112
  float lw[16], lb[16];
  {
    const float* pw = ln_w + row_x * 128 + c0;
    const float* pb = ln_b + row_x * 128 + c0;
#pragma unroll
    for (int i = 0; i < 4; ++i) {
      float4 a = *(const float4*)(pw + i * 4);
      lw[i*4+0]=a.x; lw[i*4+1]=a.y; lw[i*4+2]=a.z; lw[i*4+3]=a.w;
      float4 b = *(const float4*)(pb + i * 4);
      lb[i*4+0]=b.x; lb[i*4+1]=b.y; lb[i*4+2]=b.z; lb[i*4+3]=b.w;
    }
  }

  // ---- prologue: row0 load+reduce; H(0); row1 load+reduce (paid once per 32 rows) ----
  float xvC[16], xvN[16];
  {
    const float* xp = x + base + (size_t)row_x * 128 + c0;
#pragma unroll
    for (int i = 0; i < 4; ++i) {
      float4 a = *(const float4*)(xp + i * 4);
      xvC[i*4+0]=a.x; xvC[i*4+1]=a.y; xvC[i*4+2]=a.z; xvC[i*4+3]=a.w;
    }
  }
  {
    float s1 = 0.f, s2 = 0.f;
#pragma unroll
    for (int i = 0; i < 16; ++i) { s1 += xvC[i]; s2 += xvC[i] * xvC[i]; }
#pragma unroll
    for (int off = 32; off > 0; off >>= 1) {
      s1 += __shfl_xor(s1, off, 64);
      s2 += __shfl_xor(s2, off, 64);
    }
    if (lane == 0) { redS[w] = s1; redS[8 + w] = s2; }
  }
  bar_lds();  // redS[0] visible
  {
    // H(0): pack row0 -> sA[0]
    float t1 = 0.f, t2 = 0.f;
#pragma unroll
    for (int p = 0; p < 8; ++p) { t1 += redS[p]; t2 += redS[8 + p]; }
    const float mu = t1 * (1.f / 8192.f);
    const float rstd = rsqrtf(t2 * (1.f / 8192.f) - mu * mu + 1e-5f);
    unsigned char* sA0 = smem;
#pragma unroll
    for (int h = 0; h < 2; ++h) {
      ushort8v t;
#pragma unroll
      for (int j = 0; j < 8; ++j)
        t[j] = f2bf((xvC[h*8+j] - mu) * rstd * lw[h*8+j] + lb[h*8+j]);
      *(ushort8v*)(sA0 + qoff(row_x, (c0 << 1) + h * 16)) = t;
    }
    // load row1 + its reduce (exposed once per block)
    const float* xp = x + base + 8192 + (size_t)row_x * 128 + c0;
#pragma unroll
    for (int i = 0; i < 4; ++i) {
      float4 a = *(const float4*)(xp + i * 4);
      xvN[i*4+0]=a.x; xvN[i*4+1]=a.y; xvN[i*4+2]=a.z; xvN[i*4+3]=a.w;
    }
    float s1 = 0.f, s2 = 0.f;
#pragma unroll
    for (int i = 0; i < 16; ++i) { s1 += xvN[i]; s2 += xvN[i] * xvN[i]; }
#pragma unroll
    for (int off = 32; off > 0; off >>= 1) {
      s1 += __shfl_xor(s1, off, 64);
      s2 += __shfl_xor(s2, off, 64);
    }
    if (lane == 0) { redS[16 + w] = s1; redS[24 + w] = s2; }
  }
  bar_lds();  // sA[0] + redS[1] visible
#pragma unroll
  for (int i = 0; i < 16; ++i) xvC[i] = xvN[i];  // xvC = row1

#pragma unroll 1
  for (int r = 0; r < 32; ++r) {
    const int cur = r & 1, nxt = cur ^ 1;
    unsigned char* sAc  = smem + cur * 16384;
    unsigned char* sAn  = smem + nxt * 16384;
    unsigned char* sQc  = smem + 32768 + cur * 16384;
    unsigned char* sKc  = smem + 65536 + cur * 16384;
    unsigned char* sVTc = smem + 98304 + cur * 16384;
    unsigned char* sVTn = smem + 98304 + nxt * 16384;
    unsigned char* sSc  = smem + 131072 + cur * 8192;
    unsigned char* sSn  = smem + 131072 + nxt * 8192;
    float* redC = redS + cur * 16;    // lnred(r+2) target
    float* redN = redS + nxt * 16;    // H(r+1) source
    float* pPc = pPart + cur * 128;
    float* pPn = pPart + nxt * 128;
    const size_t bofs = base + (size_t)r * 8192;

    // ================= IA(r): xr(r-1) prefetch || G(r) || H(r+1) =================
    f32x4 xrP[4];
    if (r >= 1) {
      const size_t bofsP = bofs - 8192;
#pragma unroll
      for (int nt = 0; nt < 4; ++nt) {
        const int l = nt * 16 + l15;
        const int mb = (w << 4) + (l4 << 2);
        xrP[nt] = *(const f32x4*)(x + bofsP + (size_t)l * 128 + mb);
      }
    }
    // G(r): GEMM1 (col-split) from sA[cur]
#pragma unroll
    for (int mt = 0; mt < 4; ++mt) {
      bf16x8 aq[4];
#pragma unroll
      for (int kk = 0; kk < 4; ++kk)
        aq[kk] = *(const bf16x8*)(sAc + qoff(mt * 16 + l15, kk * 64 + (l4 << 4)));
      const int i0m = mt * 16 + (l4 << 2);
      f32x4 aQ = {0,0,0,0}, aK = {0,0,0,0}, aV = {0,0,0,0};
#pragma unroll
      for (int kk = 0; kk < 4; ++kk) {
        aQ = __builtin_amdgcn_mfma_f32_16x16x32_bf16(aq[kk], wf[0][kk], aQ, 0, 0, 0);
        aK = __builtin_amdgcn_mfma_f32_16x16x32_bf16(aq[kk], wf[1][kk], aK, 0, 0, 0);
        aV = __builtin_amdgcn_mfma_f32_16x16x32_bf16(aq[kk], wf[2][kk], aV, 0, 0, 0);
      }
#pragma unroll
      for (int rr = 0; rr < 4; ++rr) {
        float zq = aQ[rr] + biasQ; zq = zq > 0.f ? zq + 1.f : __expf(zq);
        *(unsigned short*)(sQc + qoff(i0m + rr, col * 2)) = f2bf(zq);
        float zk = aK[rr] + biasK; zk = zk > 0.f ? zk + 1.f : __expf(zk);
        *(unsigned short*)(sKc + qoff(i0m + rr, col * 2)) = f2bf(zk);
      }
      ushort4 pk;
      pk.x = f2bf(aV[0] + biasV); pk.y = f2bf(aV[1] + biasV);
      pk.z = f2bf(aV[2] + biasV); pk.w = f2bf(aV[3] + biasV);
      *(ushort4*)(sVTc + toff(col, i0m * 2)) = pk;
    }
    // H(r+1): stats from redS[nxt] (written in IB(r-1)/prologue); pack xvC -> sA[nxt]
    if (r < 31) {
      float t1 = 0.f, t2 = 0.f;
#pragma unroll
      for (int p = 0; p < 8; ++p) { t1 += redN[p]; t2 += redN[8 + p]; }
      const float mu = t1 * (1.f / 8192.f);
      const float rstd = rsqrtf(t2 * (1.f / 8192.f) - mu * mu + 1e-5f);
#pragma unroll
      for (int h = 0; h < 2; ++h) {
        ushort8v t;
#pragma unroll
        for (int j = 0; j < 8; ++j)
          t[j] = f2bf((xvC[h*8+j] - mu) * rstd * lw[h*8+j] + lb[h*8+j]);
        *(ushort8v*)(sAn + qoff(row_x, (c0 << 1) + h * 16)) = t;
      }
      if (r < 30) {  // issue load of row r+2 (reduced in IB(r), packed in IA(r+1))
        const float* xp = x + bofs + 2 * 8192 + (size_t)row_x * 128 + c0;
#pragma unroll
        for (int i = 0; i < 4; ++i) {
          float4 a = *(const float4*)(xp + i * 4);
          xvN[i*4+0]=a.x; xvN[i*4+1]=a.y; xvN[i*4+2]=a.z; xvN[i*4+3]=a.w;
        }
      }
    }
    bar_lds();  // end IA(r)

    // ================= IB(r): S(r) || lnred(r+2) || P(r-1) =================
    // S(r): S = Q K^T from sQ/sK[cur]; rowsum partials -> pPart[cur]; raw S -> sS[cur]
    const int rt = w >> 1;
    const int h2 = w & 1;
    const int i0s = rt * 16 + (l4 << 2);
    {
      bf16x8 aq[4];
#pragma unroll
      for (int kk = 0; kk < 4; ++kk)
        aq[kk] = *(const bf16x8*)(sQc + qoff(rt * 16 + l15, kk * 64 + (l4 << 4)));
      f32x4 accS[2];
#pragma unroll
      for (int nt = 0; nt < 2; ++nt) {
        const int ntg = h2 * 2 + nt;
        f32x4 acc = {0,0,0,0};
#pragma unroll
        for (int kk = 0; kk < 4; ++kk) {
          bf16x8 bk_ = *(const bf16x8*)(sKc + qoff(ntg * 16 + l15, kk * 64 + (l4 << 4)));
          acc = __builtin_amdgcn_mfma_f32_16x16x32_bf16(aq[kk], bk_, acc, 0, 0, 0);
        }
        accS[nt] = acc;
      }
      float p[4];
#pragma unroll
      for (int rr = 0; rr < 4; ++rr) p[rr] = accS[0][rr] + accS[1][rr];
#pragma unroll
      for (int off = 1; off < 16; off <<= 1) {
#pragma unroll
        for (int rr = 0; rr < 4; ++rr) p[rr] += __shfl_xor(p[rr], off, 64);
      }
      if (l15 == 0) {
#pragma unroll
        for (int rr = 0; rr < 4; ++rr)
          pPc[w * 16 + (l4 << 2) + rr] = p[rr];
      }
#pragma unroll
      for (int nt = 0; nt < 2; ++nt) {
        const int ntg = h2 * 2 + nt;
#pragma unroll
        for (int rr = 0; rr < 4; ++rr)
          *(unsigned short*)(sSc + toff(i0s + rr, (ntg * 16 + l15) * 2)) = f2bf(accS[nt][rr]);
      }
    }
    // lnred(r+2): reduce xvN -> redS[cur]
    if (r < 30) {
      float n1 = 0.f, n2 = 0.f;
#pragma unroll
      for (int i = 0; i < 16; ++i) { n1 += xvN[i]; n2 += xvN[i] * xvN[i]; }
#pragma unroll
      for (int off = 32; off > 0; off >>= 1) {
        n1 += __shfl_xor(n1, off, 64);
        n2 += __shfl_xor(n2, off, 64);
      }
      if (lane == 0) { redC[w] = n1; redC[8 + w] = n2; }
    }
    // P(r-1): PV + residual + store from buffers [nxt]
    if (r >= 1) {
      const size_t bofsP = bofs - 8192;
      float nv[4];
#pragma unroll
      for (int nt = 0; nt < 4; ++nt)
        nv[nt] = 1.f / (pPn[nt * 32 + l15] + pPn[nt * 32 + 16 + l15] + 1e-7f);
      bf16x8 av[2];
#pragma unroll
      for (int kk = 0; kk < 2; ++kk)
        av[kk] = *(const bf16x8*)(sVTn + toff((w << 4) + l15, kk * 64 + (l4 << 4)));
#pragma unroll
      for (int nt = 0; nt < 4; ++nt) {
        bf16x8 bs0 = *(const bf16x8*)(sSn + toff(nt * 16 + l15, (l4 << 4)));
        bf16x8 bs1 = *(const bf16x8*)(sSn + toff(nt * 16 + l15, 64 + (l4 << 4)));
        f32x4 acc = {0,0,0,0};
        acc = __builtin_amdgcn_mfma_f32_16x16x32_bf16(av[0], bs0, acc, 0, 0, 0);
        acc = __builtin_amdgcn_mfma_f32_16x16x32_bf16(av[1], bs1, acc, 0, 0, 0);
        const int l = nt * 16 + l15;
        const int mb = (w << 4) + (l4 << 2);
        const size_t idx = bofsP + (size_t)l * 128 + mb;
        f32x4 o;
        o[0] = acc[0] * nv[nt] + xrP[nt][0];
        o[1] = acc[1] * nv[nt] + xrP[nt][1];
        o[2] = acc[2] * nv[nt] + xrP[nt][2];
        o[3] = acc[3] * nv[nt] + xrP[nt][3];
        *(f32x4*)(out + idx) = o;
      }
    }
    bar_lds();  // end IB(r)

    if (r < 30) {
#pragma unroll
      for (int i = 0; i < 16; ++i) xvC[i] = xvN[i];
    }
  }

  // ================= epilogue: P(31) (buffers parity 1) =================
  {
    const size_t bofsP = base + 31 * 8192;
    unsigned char* sVT1 = smem + 98304 + 16384;
    unsigned char* sS1  = smem + 131072 + 8192;
    float* pP1 = pPart + 128;
    f32x4 xr7[4];
#pragma unroll
    for (int nt = 0; nt < 4; ++nt) {
      const int l = nt * 16 + l15;
      const int mb = (w << 4) + (l4 << 2);
      xr7[nt] = *(const f32x4*)(x + bofsP + (size_t)l * 128 + mb);
    }
    float nv[4];
#pragma unroll
    for (int nt = 0; nt < 4; ++nt)
      nv[nt] = 1.f / (pP1[nt * 32 + l15] + pP1[nt * 32 + 16 + l15] + 1e-7f);
    bf16x8 av[2];
#pragma unroll
    for (int kk = 0; kk < 2; ++kk)
      av[kk] = *(const bf16x8*)(sVT1 + toff((w << 4) + l15, kk * 64 + (l4 << 4)));
#pragma unroll
    for (int nt = 0; nt < 4; ++nt) {
      bf16x8 bs0 = *(const bf16x8*)(sS1 + toff(nt * 16 + l15, (l4 << 4)));
      bf16x8 bs1 = *(const bf16x8*)(sS1 + toff(nt * 16 + l15, 64 + (l4 << 4)));
      f32x4 acc = {0,0,0,0};
      acc = __builtin_amdgcn_mfma_f32_16x16x32_bf16(av[0], bs0, acc, 0, 0, 0);
      acc = __builtin_amdgcn_mfma_f32_16x16x32_bf16(av[1], bs1, acc, 0, 0, 0);
      const int l = nt * 16 + l15;
      const int mb = (w << 4) + (l4 << 2);
      const size_t idx = bofsP + (size_t)l * 128 + mb;
      f32x4 o;
      o[0] = acc[0] * nv[nt] + xr7[nt][0];
      o[1] = acc[1] * nv[nt] + xr7[nt][1];
      o[2] = acc[2] * nv[nt] + xr7[nt][2];
      o[3] = acc[3] * nv[nt] + xr7[nt][3];
      *(f32x4*)(out + idx) = o;
    }
  }
}

extern "C" void kernel_launch(void* const* d_in, const int* in_sizes, int n_in,
                              void* d_out, int out_size, void* d_ws, size_t ws_size,
                              hipStream_t stream) {
  const float* x   = (const float*)d_in[0];
  const float* Wq  = (const float*)d_in[1];
  const float* bq  = (const float*)d_in[2];
  const float* Wk  = (const float*)d_in[3];
  const float* bk  = (const float*)d_in[4];
  const float* Wv  = (const float*)d_in[5];
  const float* bv  = (const float*)d_in[6];
  const float* lnw = (const float*)d_in[7];
  const float* lnb = (const float*)d_in[8];
  float* out = (float*)d_out;

  fused_attn<<<256, 512, 0, stream>>>(x, Wq, Wk, Wv, bq, bk, bv, lnw, lnb, out);
}